// Round 5
// baseline (590.608 us; speedup 1.0000x reference)
//
#include <hip/hip_runtime.h>
#include <cstdint>
#include <cstddef>

typedef unsigned short u16;
typedef unsigned int u32;
typedef short bfrag __attribute__((ext_vector_type(8)));   // 8 bf16 bit-patterns (4 VGPR)
typedef __bf16 yfrag __attribute__((ext_vector_type(8)));  // alt spelling for the builtin
typedef float f4 __attribute__((ext_vector_type(4)));

// ---------- scalar bf16 helpers (RNE) ----------
__device__ __forceinline__ u16 f2bs(float f) {
  union { float f; u32 u; } x; x.f = f;
  u32 r = x.u + 0x7fffu + ((x.u >> 16) & 1u);
  return (u16)(r >> 16);
}
__device__ __forceinline__ float bs2f(u16 s) {
  union { u32 u; float f; } x; x.u = ((u32)s) << 16;
  return x.f;
}
// packed bf16 convert: D.lo = bf16(lo), D.hi = bf16(hi), RNE (no builtin on gfx950)
__device__ __forceinline__ u32 cvtpk_bf16(float lo, float hi) {
  u32 d;
  asm("v_cvt_pk_bf16_f32 %0, %1, %2" : "=v"(d) : "v"(lo), "v"(hi));
  return d;
}

// ---------- MFMA wrapper: robust to either builtin operand type ----------
template <typename T>
__device__ __forceinline__ auto mfma_sel(T a, T b, f4 c, int)
    -> decltype(__builtin_amdgcn_mfma_f32_16x16x32_bf16(a, b, c, 0, 0, 0)) {
  return __builtin_amdgcn_mfma_f32_16x16x32_bf16(a, b, c, 0, 0, 0);
}
template <typename T>
__device__ __forceinline__ f4 mfma_sel(T a, T b, f4 c, long) {
  yfrag ya = __builtin_bit_cast(yfrag, a);
  yfrag yb = __builtin_bit_cast(yfrag, b);
  return __builtin_amdgcn_mfma_f32_16x16x32_bf16(ya, yb, c, 0, 0, 0);
}
__device__ __forceinline__ f4 MFMA(bfrag a, bfrag b, f4 c) {
  return mfma_sel(a, b, c, 0);
}

// ---------- async global->LDS, 16B per lane, wave-uniform LDS base ----------
__device__ __forceinline__ void gl2lds16(const u16* g, u16* l) {
  __builtin_amdgcn_global_load_lds(
      (__attribute__((address_space(1))) void*)(g),
      (__attribute__((address_space(3))) void*)(l), 16, 0, 0);
}

// =====================================================================
// fp32 -> bf16 elementwise convert, x and ctx fused in one launch.
// =====================================================================
__global__ __launch_bounds__(256) void cvt2(const float* __restrict__ x,
                                            u16* __restrict__ xbf,
                                            const float* __restrict__ ctx,
                                            u16* __restrict__ ctxb) {
  int i = blockIdx.x * 256 + threadIdx.x;
  const float* src; u16* dst;
  if (i < 3145728) {
    src = x; dst = xbf;
  } else {
    i -= 3145728;
    if (i >= 147648) return;
    src = ctx; dst = ctxb;
  }
  const float4* s4 = (const float4*)src;
  float4 a = s4[(size_t)i * 2];
  float4 b = s4[(size_t)i * 2 + 1];
  uint4 o;
  o.x = cvtpk_bf16(a.x, a.y);
  o.y = cvtpk_bf16(a.z, a.w);
  o.z = cvtpk_bf16(b.x, b.y);
  o.w = cvtpk_bf16(b.z, b.w);
  ((uint4*)dst)[i] = o;
}

// =====================================================================
// transpose 1536x1536 fp32 -> bf16, 6 weights in one launch (z picks)
// =====================================================================
__global__ __launch_bounds__(256) void transpose6(
    const float* s0, const float* s1, const float* s2, const float* s3,
    const float* s4, const float* s5, u16* d0, u16* d1, u16* d2, u16* d3,
    u16* d4, u16* d5) {
  const float* src; u16* dst;
  switch (blockIdx.z) {
    case 0: src = s0; dst = d0; break;
    case 1: src = s1; dst = d1; break;
    case 2: src = s2; dst = d2; break;
    case 3: src = s3; dst = d3; break;
    case 4: src = s4; dst = d4; break;
    default: src = s5; dst = d5; break;
  }
  __shared__ float tile[32][33];
  int tx = threadIdx.x, ty = threadIdx.y;
  int bx = blockIdx.x * 32, by = blockIdx.y * 32;
#pragma unroll
  for (int j = 0; j < 4; j++)
    tile[ty + j * 8][tx] = src[(size_t)(by + ty + j * 8) * 1536 + bx + tx];
  __syncthreads();
#pragma unroll
  for (int j = 0; j < 4; j++)
    dst[(size_t)(bx + ty + j * 8) * 1536 + by + tx] = f2bs(tile[tx][ty + j * 8]);
}

// =====================================================================
// Deep-pipelined bf16 GEMM: C = A(Mx1536) * Bt(1536x1536)^T + bias.
// BM=BN=256, 512 threads = 8 waves (2M x 4N), wave tile 128x64.
// m201-equivalent schedule: K=32 sub-tiles in a 4-slot LDS ring
// (4 x 16KB per matrix = 128 KiB). Per sub-tile, 2 phases of
// {4-8 ds_read_b128 || 2 global_load_lds(tile t+3) -> s_barrier ->
//  lgkmcnt(0) -> setprio(1) 16 MFMA setprio(0) -> s_barrier},
// one counted vmcnt(8) per sub-tile (tail 4 -> 0) publishing tile t+1
// while t+2/t+3 stay in flight. Staging t+3 reuses slot (t-1)&3 whose
// reads finished a full tile earlier behind two barriers (race-free).
// Conflict-free LDS: row r packs global rows {r, r+128} as 8 chunks of
// 16B; chunk position = (half*4 + quad) ^ (r&7) applied on the global
// fetch side (LDS linear) AND the ds_read side -> every aligned 8-lane
// octet of a ds_read_b128 covers 8 distinct 16B slots (verified: round-4
// variant of this swizzle measured 0 bank conflicts).
// epi: 0 = bf16 C[m][n], 1 = bf16 C^T (dst[n*ldT+m]), 2 = fp32 C[m][n]
// =====================================================================
__device__ __forceinline__ void gemm256_core(
    const u16* __restrict__ A, const u16* __restrict__ Bt,
    const float* __restrict__ bias, void* __restrict__ outp,
    int Mreal, int ldT, int epi, int bx, int by, u16* As, u16* Bs) {
  const int tid = threadIdx.x;
  const int w = tid >> 6, lane = tid & 63;
  const int quad = lane >> 4, l15 = lane & 15;
  const int wm = w >> 2, wn = w & 3;  // 2M x 4N wave grid
  const int m0 = bx * 256, n0 = by * 256;

  f4 acc[8][4];
#pragma unroll
  for (int i = 0; i < 8; i++)
#pragma unroll
    for (int j = 0; j < 4; j++) acc[i][j] = f4{0.f, 0.f, 0.f, 0.f};

  // staging thread map: call j covers LDS chunk s = j*512 + w*64 + lane;
  // r = j*64 + w*8 + (lane>>3), cpos = lane&7, c = cpos ^ (r&7) where
  // r&7 == lane>>3; half = c>>2, qsrc = c&3; global row = half*128 + r.
  const int g = lane >> 3;
  const int c_ = (lane & 7) ^ g;
  const int R0 = (c_ >> 2) * 128 + w * 8 + g;  // call j=0 source row; j=1: +64
  const int qs = (c_ & 3) * 8;                 // source col offset (u16)
  const u16* Ab = A + (size_t)m0 * 1536;
  const u16* Bb = Bt + (size_t)n0 * 1536;

#define STG(Gb, Ls, t)                                                     \
  {                                                                        \
    u16* d_ = (Ls) + ((t) & 3) * 8192;                                     \
    const u16* s_ = (Gb) + (size_t)(t) * 32 + qs;                          \
    gl2lds16(s_ + (size_t)R0 * 1536, d_ + (w * 64) * 8);                   \
    gl2lds16(s_ + (size_t)(R0 + 64) * 1536, d_ + (512 + w * 64) * 8);      \
  }

  // prologue: sub-tiles 0,1,2 in flight (12 calls/wave)
  STG(Ab, As, 0); STG(Bb, Bs, 0);
  STG(Ab, As, 1); STG(Bb, Bs, 1);
  STG(Ab, As, 2); STG(Bb, Bs, 2);
  asm volatile("s_waitcnt vmcnt(8)" ::: "memory");  // tile 0 landed
  __builtin_amdgcn_s_barrier();

  for (int kt = 0; kt < 48; ++kt) {
    const u16* Asb = As + (kt & 3) * 8192;
    const u16* Bsb = Bs + (kt & 3) * 8192;

    // ---- phase A: bf[0..3] + af[0..3], stage A(t+3), 16 MFMA
    bfrag bf[4], af[4];
#pragma unroll
    for (int nf = 0; nf < 4; nf++) {
      const int br = (wn & 1) * 64 + nf * 16 + l15;
      bf[nf] = *(const bfrag*)(Bsb + br * 64 +
                               ((((wn >> 1) * 4 + quad) ^ (br & 7)) * 8));
    }
#pragma unroll
    for (int mf = 0; mf < 4; mf++) {
      const int ar = mf * 16 + l15;
      af[mf] = *(const bfrag*)(Asb + ar * 64 +
                               (((wm * 4 + quad) ^ (ar & 7)) * 8));
    }
    if (kt < 45) STG(Ab, As, kt + 3);
    __builtin_amdgcn_s_barrier();
    asm volatile("s_waitcnt lgkmcnt(0)" ::: "memory");
    __builtin_amdgcn_s_setprio(1);
#pragma unroll
    for (int mf = 0; mf < 4; mf++)
#pragma unroll
      for (int nf = 0; nf < 4; nf++)
        acc[mf][nf] = MFMA(af[mf], bf[nf], acc[mf][nf]);
    __builtin_amdgcn_s_setprio(0);
    __builtin_amdgcn_s_barrier();

    // ---- phase B: af[4..7], stage B(t+3), 16 MFMA, publish t+1
    bfrag af2[4];
#pragma unroll
    for (int mf = 0; mf < 4; mf++) {
      const int ar = (mf + 4) * 16 + l15;
      af2[mf] = *(const bfrag*)(Asb + ar * 64 +
                                (((wm * 4 + quad) ^ (ar & 7)) * 8));
    }
    if (kt < 45) STG(Bb, Bs, kt + 3);
    __builtin_amdgcn_s_barrier();
    asm volatile("s_waitcnt lgkmcnt(0)" ::: "memory");
    __builtin_amdgcn_s_setprio(1);
#pragma unroll
    for (int mf = 0; mf < 4; mf++)
#pragma unroll
      for (int nf = 0; nf < 4; nf++)
        acc[mf + 4][nf] = MFMA(af2[mf], bf[nf], acc[mf + 4][nf]);
    __builtin_amdgcn_s_setprio(0);
    // counted publish of sub-tile kt+1: t+2/t+3 (8 calls) stay in flight
    if (kt < 45)
      asm volatile("s_waitcnt vmcnt(8)" ::: "memory");
    else if (kt == 45)
      asm volatile("s_waitcnt vmcnt(4)" ::: "memory");
    else if (kt == 46)
      asm volatile("s_waitcnt vmcnt(0)" ::: "memory");
    __builtin_amdgcn_s_barrier();
  }
#undef STG

  float bcol[4];
#pragma unroll
  for (int nf = 0; nf < 4; nf++) bcol[nf] = bias[n0 + wn * 64 + nf * 16 + l15];

  if (epi == 1) {
    u16* dst = (u16*)outp;
#pragma unroll
    for (int mf = 0; mf < 8; mf++)
#pragma unroll
      for (int r = 0; r < 4; r++) {
        int row = m0 + wm * 128 + mf * 16 + quad * 4 + r;
        if (row < Mreal) {
#pragma unroll
          for (int nf = 0; nf < 4; nf++) {
            int col = n0 + wn * 64 + nf * 16 + l15;
            dst[(size_t)col * ldT + row] = f2bs(acc[mf][nf][r] + bcol[nf]);
          }
        }
      }
  } else if (epi == 0) {
    u16* dst = (u16*)outp;
#pragma unroll
    for (int mf = 0; mf < 8; mf++)
#pragma unroll
      for (int r = 0; r < 4; r++) {
        int row = m0 + wm * 128 + mf * 16 + quad * 4 + r;
        if (row < Mreal) {
#pragma unroll
          for (int nf = 0; nf < 4; nf++) {
            int col = n0 + wn * 64 + nf * 16 + l15;
            dst[(size_t)row * 1536 + col] = f2bs(acc[mf][nf][r] + bcol[nf]);
          }
        }
      }
  } else {
    float* dst = (float*)outp;
#pragma unroll
    for (int mf = 0; mf < 8; mf++)
#pragma unroll
      for (int r = 0; r < 4; r++) {
        int row = m0 + wm * 128 + mf * 16 + quad * 4 + r;
        if (row < Mreal) {
#pragma unroll
          for (int nf = 0; nf < 4; nf++) {
            int col = n0 + wn * 64 + nf * 16 + l15;
            dst[(size_t)row * 1536 + col] = acc[mf][nf][r] + bcol[nf];
          }
        }
      }
  }
}

// mode 0 (432 blocks): [0,384) q-proj (64x6 tiles of 256^2), then smalls:
// [384,396) k_txt, [396,408) k_img, [408,420) v_txt, [420,432) v_img
// mode 1 (384 blocks): output projection (fp32 epi).
// Single core call site (round-1 lesson). Bijective XCD swizzle (grid%8==0).
__global__ __launch_bounds__(512, 1) void gemm256(
    const u16* __restrict__ xbf, const u16* __restrict__ wqT,
    const float* __restrict__ bq, u16* __restrict__ qb,
    const u16* __restrict__ ctxb, const u16* __restrict__ wkT,
    const float* __restrict__ bk, u16* __restrict__ ktxt,
    const u16* __restrict__ wakT, const float* __restrict__ bak,
    u16* __restrict__ kimg, const u16* __restrict__ wvT,
    const float* __restrict__ bv, u16* __restrict__ vtt,
    const u16* __restrict__ wavT, const float* __restrict__ bav,
    u16* __restrict__ vti, const u16* __restrict__ yb,
    const u16* __restrict__ woT, const float* __restrict__ bo,
    float* __restrict__ out, int mode) {
  extern __shared__ u16 lds[];
  u16* As = lds;
  u16* Bs = lds + 32768;
  const int cpx = gridDim.x >> 3;  // grids are multiples of 8
  int id = (blockIdx.x & 7) * cpx + (blockIdx.x >> 3);
  const u16* ctxt = ctxb + 257 * 1536;
  const u16* A; const u16* Bt; const float* bias; void* outp;
  int Mreal, ldT, epi, bx, by;
  if (mode == 1) {
    A = yb; Bt = woT; bias = bo; outp = out;
    Mreal = 16384; ldT = 0; epi = 2; bx = id & 63; by = id >> 6;
  } else if (id < 384) {
    A = xbf; Bt = wqT; bias = bq; outp = qb;
    Mreal = 16384; ldT = 0; epi = 0; bx = id & 63; by = id >> 6;
  } else if (id < 396) {
    int t = id - 384;
    A = ctxt; Bt = wkT; bias = bk; outp = ktxt;
    Mreal = 512; ldT = 0; epi = 0; bx = t & 1; by = t >> 1;
  } else if (id < 408) {
    int t = id - 396;
    A = ctxb; Bt = wakT; bias = bak; outp = kimg;
    Mreal = 257; ldT = 0; epi = 0; bx = t & 1; by = t >> 1;
  } else if (id < 420) {
    int t = id - 408;
    A = ctxt; Bt = wvT; bias = bv; outp = vtt;
    Mreal = 512; ldT = 512; epi = 1; bx = t & 1; by = t >> 1;
  } else {
    int t = id - 420;
    A = ctxb; Bt = wavT; bias = bav; outp = vti;
    Mreal = 257; ldT = 264; epi = 1; bx = t & 1; by = t >> 1;
  }
  gemm256_core(A, Bt, bias, outp, Mreal, ldT, epi, bx, by, As, Bs);
}

// =====================================================================
// in-place RMSNorm over 1536 cols, bf16 buf, fp32 gain. One block per row.
// =====================================================================
__global__ __launch_bounds__(256) void rmsnorm_multi(
    u16* __restrict__ qb, const float* __restrict__ gq,
    u16* __restrict__ ktxt, const float* __restrict__ gk,
    u16* __restrict__ kimg, const float* __restrict__ gak) {
  int row = blockIdx.x;
  u16* buf; const float* g;
  if (row < 16384) {
    buf = qb; g = gq;
  } else if (row < 16896) {
    buf = ktxt; g = gk; row -= 16384;
  } else {
    buf = kimg; g = gak; row -= 16896;
  }
  const int tid = threadIdx.x;
  u32* p = (u32*)(buf + (size_t)row * 1536);  // 768 u32 per row
  const float2* g2 = (const float2*)g;
  u32 d[3];
  float v[6];
  float ss = 0.f;
#pragma unroll
  for (int j = 0; j < 3; j++) {
    d[j] = p[tid + j * 256];
    v[2 * j]     = bs2f((u16)(d[j] & 0xffffu));
    v[2 * j + 1] = bs2f((u16)(d[j] >> 16));
    ss += v[2 * j] * v[2 * j] + v[2 * j + 1] * v[2 * j + 1];
  }
#pragma unroll
  for (int off = 32; off; off >>= 1) ss += __shfl_xor(ss, off);
  __shared__ float red[4];
  if ((tid & 63) == 0) red[tid >> 6] = ss;
  __syncthreads();
  ss = red[0] + red[1] + red[2] + red[3];
  const float sc = rsqrtf(ss * (1.0f / 1536.0f) + 1e-6f);
#pragma unroll
  for (int j = 0; j < 3; j++) {
    float2 gg = g2[tid + j * 256];
    p[tid + j * 256] =
        cvtpk_bf16(v[2 * j] * sc * gg.x, v[2 * j + 1] * sc * gg.y);
  }
}

// =====================================================================
// Fused dual-segment attention (unchanged; see prior notes).
// =====================================================================
#define ATTN_SCALE 0.08838834764831845f
__global__ __launch_bounds__(256, 2) void attn_kernel(
    const u16* __restrict__ q, const u16* __restrict__ ktxt,
    const u16* __restrict__ kimg, const u16* __restrict__ vttxt,
    const u16* __restrict__ vtimg, u16* __restrict__ y) {
  __shared__ u16 Ks[64 * 128];    // 16 KB, key-interleaved, xor-swizzled
  __shared__ u16 Vs[128 * 64];    // 16 KB, feat-major, xor-swizzled
  __shared__ u16 Ps[4 * 32 * 72]; // 18 KB, per-wave P (stride 72: 16B-aligned rows)
  const int tid = threadIdx.x;
  const int w = tid >> 6, lane = tid & 63;
  const int quad = lane >> 4, l15 = lane & 15;
  const int h = blockIdx.y, hoff = h * 128;
  const int mw = blockIdx.x * 128 + w * 32;
  u16* Pw = Ps + w * (32 * 72);

  // Q frags (A-layout), resident
  bfrag qf[2][4];
#pragma unroll
  for (int rt = 0; rt < 2; rt++) {
    const u16* qrow = q + (size_t)(mw + rt * 16 + l15) * 1536 + hoff + quad * 8;
#pragma unroll
    for (int c = 0; c < 4; c++) qf[rt][c] = *(const bfrag*)(qrow + c * 32);
  }

  // staging descriptors: i = j*256+tid indexes 16B chunks in LDS-linear order
  int kko[4], kco[4], vfe[4], vco[4];
#pragma unroll
  for (int j = 0; j < 4; j++) {
    int i = j * 256 + tid;
    int s = i >> 4, cp = i & 15;           // K: slot s, chunk pos cp
    kko[j] = 4 * (s & 15) + (s >> 4);      // actual key for slot s
    kco[j] = ((cp ^ (s & 7)) * 8);         // swizzled feat offset (u16)
    int f = i >> 3, cq = i & 7;            // V: feat row f, chunk pos cq
    vfe[j] = f;
    vco[j] = ((cq ^ (f & 7)) * 8);         // swizzled key offset (u16)
  }

  f4 o[2][8];
  u32 resA[2][8][2];  // seg0 result, normalized, bf16-packed
  float lr[2][4];

  for (int seg = 0; seg < 2; seg++) {
    const u16* kp = seg ? ktxt : kimg;
    const u16* vp = seg ? vttxt : vtimg;
    const int Lk = seg ? 512 : 257;
    const int ldv = seg ? 512 : 264;
    const int nit = seg ? 8 : 5;
#pragma unroll
    for (int rt = 0; rt < 2; rt++) {
#pragma unroll
      for (int ft = 0; ft < 8; ft++) o[rt][ft] = f4{0.f, 0.f, 0.f, 0.f};
#pragma unroll
      for (int r = 0; r < 4; r++) lr[rt][r] = 0.f;
    }

    for (int it = 0; it < nit; ++it) {
      const int t0 = it * 64;
#pragma unroll
      for (int j = 0; j < 4; j++)
        gl2lds16(kp + (size_t)(t0 + kko[j]) * 1536 + hoff + kco[j],
                 Ks + (j * 256 + w * 64) * 8);
#pragma unroll
      for (int j = 0; j < 4; j++)
        gl2lds16(vp + (size_t)(hoff + vfe[j]) * ldv + t0 + vco[j],
                 Vs + (j * 256 + w * 64) * 8);
      __syncthreads();  // drains vmcnt: K/V visible

      // ---- S = Q K^T (32 MFMA); kf shared across both rowtiles
      f4 s[2][4];
#pragma unroll
      for (int rt = 0; rt < 2; rt++)
#pragma unroll
        for (int t = 0; t < 4; t++) s[rt][t] = f4{0.f, 0.f, 0.f, 0.f};
#pragma unroll
      for (int t = 0; t < 4; t++) {
        const u16* kb = Ks + (t * 16 + l15) * 128;
        bfrag kf[4];
#pragma unroll
        for (int c = 0; c < 4; c++)
          kf[c] = *(const bfrag*)(kb + (((c * 4 + quad) ^ (l15 & 7)) * 8));
#pragma unroll
        for (int rt = 0; rt < 2; rt++)
#pragma unroll
          for (int c = 0; c < 4; c++)
            s[rt][t] = MFMA(qf[rt][c], kf[c], s[rt][t]);
      }

      // ---- softmax, fixed max = 0; tile t col l15 = key 4*l15+t
      if (t0 + 64 <= Lk) {
#pragma unroll
        for (int rt = 0; rt < 2; rt++)
#pragma unroll
          for (int t = 0; t < 4; t++)
#pragma unroll
            for (int r = 0; r < 4; r++) {
              float p = __expf(s[rt][t][r] * ATTN_SCALE);
              s[rt][t][r] = p;
              lr[rt][r] += p;
            }
      } else {
#pragma unroll
        for (int t = 0; t < 4; t++) {
          bool ok = (t0 + 4 * l15 + t) < Lk;
#pragma unroll
          for (int rt = 0; rt < 2; rt++)
#pragma unroll
            for (int r = 0; r < 4; r++) {
              float p = ok ? __expf(s[rt][t][r] * ATTN_SCALE) : 0.f;
              s[rt][t][r] = p;
              lr[rt][r] += p;
            }
        }
      }

      // ---- P transpose: keys 4*l15..+3 consecutive -> b64 writes
#pragma unroll
      for (int rt = 0; rt < 2; rt++)
#pragma unroll
        for (int r = 0; r < 4; r++) {
          u32 lo = cvtpk_bf16(s[rt][0][r], s[rt][1][r]);
          u32 hi = cvtpk_bf16(s[rt][2][r], s[rt][3][r]);
          *(uint2*)(Pw + (rt * 16 + quad * 4 + r) * 72 + l15 * 4) =
              make_uint2(lo, hi);
        }
      asm volatile("s_waitcnt lgkmcnt(0)" ::: "memory");
      bfrag pf[2][2];
#pragma unroll
      for (int rt = 0; rt < 2; rt++)
#pragma unroll
        for (int hf = 0; hf < 2; hf++)
          pf[rt][hf] =
              *(const bfrag*)(Pw + (rt * 16 + l15) * 72 + hf * 32 + quad * 8);

      // ---- O += P V (32 MFMA); vf shared across rowtiles
#pragma unroll
      for (int ft = 0; ft < 8; ft++) {
        const u16* vb = Vs + (ft * 16 + l15) * 64;
#pragma unroll
        for (int hf = 0; hf < 2; hf++) {
          bfrag vf = *(const bfrag*)(vb + (((hf * 4 + quad) ^ (l15 & 7)) * 8));
#pragma unroll
          for (int rt = 0; rt < 2; rt++)
            o[rt][ft] = MFMA(pf[rt][hf], vf, o[rt][ft]);
        }
      }
      __syncthreads();  // all waves done with K/V before next stage
    }

    // ---- reduce l over the 16-lane col group; lr := 1/l
#pragma unroll
    for (int rt = 0; rt < 2; rt++)
#pragma unroll
      for (int r = 0; r < 4; r++) {
        float v = lr[rt][r];
        v += __shfl_xor(v, 1);
        v += __shfl_xor(v, 2);
        v += __shfl_xor(v, 4);
        v += __shfl_xor(v, 8);
        lr[rt][r] = 1.0f / v;
      }
    if (seg == 0) {
#pragma unroll
      for (int rt = 0; rt < 2; rt++)
#pragma unroll
        for (int ft = 0; ft < 8; ft++) {
          resA[rt][ft][0] = cvtpk_bf16(o[rt][ft][0] * lr[rt][0],
                                       o[rt][ft][1] * lr[rt][1]);
          resA[rt][ft][1] = cvtpk_bf16(o[rt][ft][2] * lr[rt][2],
                                       o[rt][ft][3] * lr[rt][3]);
        }
    }
  }

  // ---- epilogue: y = img_norm + txt_norm (bf16)
#pragma unroll
  for (int rt = 0; rt < 2; rt++)
#pragma unroll
    for (int ft = 0; ft < 8; ft++) {
      float ra[4];
      ra[0] = bs2f((u16)(resA[rt][ft][0] & 0xffffu));
      ra[1] = bs2f((u16)(resA[rt][ft][0] >> 16));
      ra[2] = bs2f((u16)(resA[rt][ft][1] & 0xffffu));
      ra[3] = bs2f((u16)(resA[rt][ft][1] >> 16));
#pragma unroll
      for (int r = 0; r < 4; r++)
        y[(size_t)(mw + rt * 16 + quad * 4 + r) * 1536 + hoff + ft * 16 + l15] =
            f2bs(ra[r] + o[rt][ft][r] * lr[rt][r]);
    }
}

// =====================================================================
extern "C" void kernel_launch(void* const* d_in, const int* in_sizes, int n_in,
                              void* d_out, int out_size, void* d_ws,
                              size_t ws_size, hipStream_t stream) {
  const float* x   = (const float*)d_in[0];
  const float* ctx = (const float*)d_in[1];
  const float* Wq  = (const float*)d_in[3];
  const float* bq  = (const float*)d_in[4];
  const float* Wk  = (const float*)d_in[5];
  const float* bk  = (const float*)d_in[6];
  const float* Wv  = (const float*)d_in[7];
  const float* bv  = (const float*)d_in[8];
  const float* Wak = (const float*)d_in[9];
  const float* bak = (const float*)d_in[10];
  const float* Wav = (const float*)d_in[11];
  const float* bav = (const float*)d_in[12];
  const float* Wo  = (const float*)d_in[13];
  const float* bo  = (const float*)d_in[14];
  const float* gq  = (const float*)d_in[15];
  const float* gk  = (const float*)d_in[16];
  const float* gak = (const float*)d_in[17];
  float* out = (float*)d_out;

  // workspace layout (u16 elements); ~136 MB
  // NOTE: attn over-reads kimg rows [257,320) -> lands in vti (finite bf16,
  // masked) and vti cols beyond 264 -> stays within vti/vtt (finite, P==0).
  // gemm256 small-GEMM paths over-read A rows up to 511 -> stay inside ctxb
  // (769 rows; ctxt rows up to 511 = ctxb row 768, exact fit).
  u16* xbf  = (u16*)d_ws;                 // 16384x1536 bf16 x; reused as y later
  u16* qb   = xbf + 25165824;             // 16384x1536 q
  u16* ctxb = qb + 25165824;              // 769x1536 context bf16
  u16* wqT  = ctxb + 1181184;             // 6 transposed bf16 weights (NxK)
  u16* wkT  = wqT + 2359296;
  u16* wvT  = wkT + 2359296;
  u16* wakT = wvT + 2359296;
  u16* wavT = wakT + 2359296;
  u16* woT  = wavT + 2359296;
  u16* ktxt = woT + 2359296;              // 512x1536
  u16* kimg = ktxt + 786432;              // 257x1536
  u16* vti  = kimg + 394752;              // V^T img: 1536x264
  u16* vtt  = vti + 405504;               // V^T txt: 1536x512 (exact, last)

  // 1) dtype conversions (x + ctx fused)
  cvt2<<<12865, 256, 0, stream>>>(x, xbf, ctx, ctxb);
  transpose6<<<dim3(48, 48, 6), dim3(32, 8), 0, stream>>>(
      Wq, Wk, Wv, Wak, Wav, Wo, wqT, wkT, wvT, wakT, wavT, woT);

  // 2) all five projections in ONE deep-pipelined launch (128 KiB dyn LDS)
  gemm256<<<432, 512, 131072, stream>>>(xbf, wqT, bq, qb,
                                        ctxb, wkT, bk, ktxt,
                                        wakT, bak, kimg,
                                        wvT, bv, vtt,
                                        wavT, bav, vti,
                                        xbf, woT, bo, out, 0);

  // 3) RMSNorms (in-place, full 1536-dim rows), one launch for q/k/k_img
  rmsnorm_multi<<<17153, 256, 0, stream>>>(qb, gq, ktxt, gk, kimg, gak);

  // 4) fused dual attention -> y (reuses xbf region)
  attn_kernel<<<dim3(128, 12), 256, 0, stream>>>(qb, ktxt, kimg, vtt, vti, xbf);

  // 5) output projection, fp32 (same kernel, mode 1)
  gemm256<<<384, 512, 131072, stream>>>(xbf, wqT, bq, qb,
                                        ctxb, wkT, bk, ktxt,
                                        wakT, bak, kimg,
                                        wvT, bv, vtt,
                                        wavT, bav, vti,
                                        xbf, woT, bo, out, 1);
}

// Round 6
// 570.875 us; speedup vs baseline: 1.0346x; 1.0346x over previous
//
#include <hip/hip_runtime.h>
#include <cstdint>
#include <cstddef>

typedef unsigned short u16;
typedef unsigned int u32;
typedef short bfrag __attribute__((ext_vector_type(8)));   // 8 bf16 bit-patterns (4 VGPR)
typedef __bf16 yfrag __attribute__((ext_vector_type(8)));  // alt spelling for the builtin
typedef float f4 __attribute__((ext_vector_type(4)));

// ---------- scalar bf16 helpers (RNE) ----------
__device__ __forceinline__ u16 f2bs(float f) {
  union { float f; u32 u; } x; x.f = f;
  u32 r = x.u + 0x7fffu + ((x.u >> 16) & 1u);
  return (u16)(r >> 16);
}
__device__ __forceinline__ float bs2f(u16 s) {
  union { u32 u; float f; } x; x.u = ((u32)s) << 16;
  return x.f;
}
// packed bf16 convert: D.lo = bf16(lo), D.hi = bf16(hi), RNE (no builtin on gfx950)
__device__ __forceinline__ u32 cvtpk_bf16(float lo, float hi) {
  u32 d;
  asm("v_cvt_pk_bf16_f32 %0, %1, %2" : "=v"(d) : "v"(lo), "v"(hi));
  return d;
}

// ---------- MFMA wrapper: robust to either builtin operand type ----------
template <typename T>
__device__ __forceinline__ auto mfma_sel(T a, T b, f4 c, int)
    -> decltype(__builtin_amdgcn_mfma_f32_16x16x32_bf16(a, b, c, 0, 0, 0)) {
  return __builtin_amdgcn_mfma_f32_16x16x32_bf16(a, b, c, 0, 0, 0);
}
template <typename T>
__device__ __forceinline__ f4 mfma_sel(T a, T b, f4 c, long) {
  yfrag ya = __builtin_bit_cast(yfrag, a);
  yfrag yb = __builtin_bit_cast(yfrag, b);
  return __builtin_amdgcn_mfma_f32_16x16x32_bf16(ya, yb, c, 0, 0, 0);
}
__device__ __forceinline__ f4 MFMA(bfrag a, bfrag b, f4 c) {
  return mfma_sel(a, b, c, 0);
}

// ---------- async global->LDS, 16B per lane, wave-uniform LDS base ----------
__device__ __forceinline__ void gl2lds16(const u16* g, u16* l) {
  __builtin_amdgcn_global_load_lds(
      (__attribute__((address_space(1))) void*)(g),
      (__attribute__((address_space(3))) void*)(l), 16, 0, 0);
}

// =====================================================================
// prep: fused fp32->bf16 convert (x + ctx) AND 6-weight transpose.
// blocks [0,12865): cvt path (i = b*256+tid indexes 8-float chunks;
//   [0,3145728) -> x, then ctx). blocks [12865, 12865+13824): transpose
//   path, b-12865 -> (z, by, bx) over 48x48x6 tiles of 32x32.
// =====================================================================
__global__ __launch_bounds__(256) void prep(
    const float* __restrict__ x, u16* __restrict__ xbf,
    const float* __restrict__ ctx, u16* __restrict__ ctxb,
    const float* s0, const float* s1, const float* s2, const float* s3,
    const float* s4, const float* s5, u16* d0, u16* d1, u16* d2,
    u16* d3, u16* d4, u16* d5) {
  __shared__ float tile[32][33];
  const int tid = threadIdx.x;
  int b = blockIdx.x;
  if (b < 12865) {
    int i = b * 256 + tid;
    const float* src; u16* dst;
    if (i < 3145728) {
      src = x; dst = xbf;
    } else {
      i -= 3145728;
      if (i >= 147648) return;
      src = ctx; dst = ctxb;
    }
    const float4* s4p = (const float4*)src;
    float4 a = s4p[(size_t)i * 2];
    float4 c = s4p[(size_t)i * 2 + 1];
    uint4 o;
    o.x = cvtpk_bf16(a.x, a.y);
    o.y = cvtpk_bf16(a.z, a.w);
    o.z = cvtpk_bf16(c.x, c.y);
    o.w = cvtpk_bf16(c.z, c.w);
    ((uint4*)dst)[i] = o;
    return;
  }
  b -= 12865;
  const int z = b / 2304, rem = b % 2304;
  const int byy = rem / 48, bxx = rem % 48;
  const float* src; u16* dst;
  switch (z) {
    case 0: src = s0; dst = d0; break;
    case 1: src = s1; dst = d1; break;
    case 2: src = s2; dst = d2; break;
    case 3: src = s3; dst = d3; break;
    case 4: src = s4; dst = d4; break;
    default: src = s5; dst = d5; break;
  }
  const int tx = tid & 31, ty = tid >> 5;
  const int bx = bxx * 32, by = byy * 32;
#pragma unroll
  for (int j = 0; j < 4; j++)
    tile[ty + j * 8][tx] = src[(size_t)(by + ty + j * 8) * 1536 + bx + tx];
  __syncthreads();
#pragma unroll
  for (int j = 0; j < 4; j++)
    dst[(size_t)(bx + ty + j * 8) * 1536 + by + tx] = f2bs(tile[tx][ty + j * 8]);
}

// =====================================================================
// Deep-pipelined bf16 GEMM (ROUND-4 VERSION, best measured: 124 us,
// SQ_LDS_BANK_CONFLICT == 0): C = A(Mx1536) * Bt(1536x1536)^T + bias.
// BM=BN=256, BK=64, 512 threads = 8 waves (2M x 4N), wave tile 128x64.
// LDS: 2-buffer ring over 64-K tiles (A,B: 32KB per buf) = 128 KiB.
// Conflict-free layout: row-major [256][64] bf16 (128B rows) with per-row
// 16B-chunk rotation c' = c ^ (R&7), applied on the global-fetch side
// (LDS dest stays linear for global_load_lds) AND on the ds_read side.
// Schedule per K-tile: [vmcnt(8)+barrier] frags + 32 MFMA (kk0),
// frags (kk1), [lgkmcnt(0)+barrier], stage kt+2, 32 MFMA (kk1).
// epi: 0 = bf16 C[m][n], 1 = bf16 C^T (dst[n*ldT+m]), 2 = fp32 C[m][n]
// =====================================================================
__device__ __forceinline__ void gemm256_core(
    const u16* __restrict__ A, const u16* __restrict__ Bt,
    const float* __restrict__ bias, void* __restrict__ outp,
    int Mreal, int ldT, int epi, int bx, int by, u16* As, u16* Bs) {
  const int tid = threadIdx.x;
  const int w = tid >> 6, lane = tid & 63;
  const int quad = lane >> 4, l15 = lane & 15;
  const int wm = w >> 2, wn = w & 3;  // 2M x 4N wave grid
  const int m0 = bx * 256, n0 = by * 256;

  f4 acc[8][4];
#pragma unroll
  for (int i = 0; i < 8; i++)
#pragma unroll
    for (int j = 0; j < 4; j++) acc[i][j] = f4{0.f, 0.f, 0.f, 0.f};

  const int rbase = w * 8 + (lane >> 3);               // row within 64-row band
  const int csrc = ((lane & 7) ^ (lane >> 3)) * 8;     // swizzled src chunk (u16)
  const u16* Ab = A + (size_t)m0 * 1536;
  const u16* Bb = Bt + (size_t)n0 * 1536;

#define STG(Gb, Ls, t)                                                      \
  {                                                                         \
    u16* d_ = (Ls) + ((t) & 1) * 16384;                                     \
    const u16* s_ = (Gb) + (size_t)(t) * 64 + csrc;                         \
    _Pragma("unroll")                                                       \
    for (int j = 0; j < 4; j++)                                             \
      gl2lds16(s_ + (size_t)(j * 64 + rbase) * 1536,                        \
               d_ + (j * 512 + w * 64) * 8);                                \
  }

  // prologue: tiles 0 and 1 in flight (16 loads/thread)
  STG(Ab, As, 0); STG(Bb, Bs, 0);
  STG(Ab, As, 1); STG(Bb, Bs, 1);

  for (int kt = 0; kt < 24; ++kt) {
    const u16* Asb = As + (kt & 1) * 16384;
    const u16* Bsb = Bs + (kt & 1) * 16384;
    if (kt < 23)
      asm volatile("s_waitcnt vmcnt(8)\n\ts_barrier" ::: "memory");
    else
      asm volatile("s_waitcnt vmcnt(0)\n\ts_barrier" ::: "memory");

    // ---- kk0: frags + 32 MFMA
    bfrag af[8], bf[4];
#pragma unroll
    for (int nf = 0; nf < 4; nf++) {
      const int R = wn * 64 + nf * 16 + l15;
      bf[nf] = *(const bfrag*)(Bsb + R * 64 + ((quad ^ (R & 7)) * 8));
    }
#pragma unroll
    for (int mf = 0; mf < 8; mf++) {
      const int R = wm * 128 + mf * 16 + l15;
      af[mf] = *(const bfrag*)(Asb + R * 64 + ((quad ^ (R & 7)) * 8));
    }
    __builtin_amdgcn_s_setprio(1);
#pragma unroll
    for (int mf = 0; mf < 8; mf++)
#pragma unroll
      for (int nf = 0; nf < 4; nf++)
        acc[mf][nf] = MFMA(af[mf], bf[nf], acc[mf][nf]);
    __builtin_amdgcn_s_setprio(0);

    // ---- kk1 frags (latency overlaps kk0 MFMA execution)
    bfrag af1[8], bf1[4];
#pragma unroll
    for (int nf = 0; nf < 4; nf++) {
      const int R = wn * 64 + nf * 16 + l15;
      bf1[nf] = *(const bfrag*)(Bsb + R * 64 + (((4 + quad) ^ (R & 7)) * 8));
    }
#pragma unroll
    for (int mf = 0; mf < 8; mf++) {
      const int R = wm * 128 + mf * 16 + l15;
      af1[mf] = *(const bfrag*)(Asb + R * 64 + (((4 + quad) ^ (R & 7)) * 8));
    }
    asm volatile("s_waitcnt lgkmcnt(0)\n\ts_barrier" ::: "memory");
    if (kt < 22) { STG(Ab, As, kt + 2); STG(Bb, Bs, kt + 2); }
    __builtin_amdgcn_s_setprio(1);
#pragma unroll
    for (int mf = 0; mf < 8; mf++)
#pragma unroll
      for (int nf = 0; nf < 4; nf++)
        acc[mf][nf] = MFMA(af1[mf], bf1[nf], acc[mf][nf]);
    __builtin_amdgcn_s_setprio(0);
  }
#undef STG

  float bcol[4];
#pragma unroll
  for (int nf = 0; nf < 4; nf++) bcol[nf] = bias[n0 + wn * 64 + nf * 16 + l15];

  if (epi == 1) {
    u16* dst = (u16*)outp;
#pragma unroll
    for (int mf = 0; mf < 8; mf++)
#pragma unroll
      for (int r = 0; r < 4; r++) {
        int row = m0 + wm * 128 + mf * 16 + quad * 4 + r;
        if (row < Mreal) {
#pragma unroll
          for (int nf = 0; nf < 4; nf++) {
            int col = n0 + wn * 64 + nf * 16 + l15;
            dst[(size_t)col * ldT + row] = f2bs(acc[mf][nf][r] + bcol[nf]);
          }
        }
      }
  } else if (epi == 0) {
    u16* dst = (u16*)outp;
#pragma unroll
    for (int mf = 0; mf < 8; mf++)
#pragma unroll
      for (int r = 0; r < 4; r++) {
        int row = m0 + wm * 128 + mf * 16 + quad * 4 + r;
        if (row < Mreal) {
#pragma unroll
          for (int nf = 0; nf < 4; nf++) {
            int col = n0 + wn * 64 + nf * 16 + l15;
            dst[(size_t)row * 1536 + col] = f2bs(acc[mf][nf][r] + bcol[nf]);
          }
        }
      }
  } else {
    float* dst = (float*)outp;
#pragma unroll
    for (int mf = 0; mf < 8; mf++)
#pragma unroll
      for (int r = 0; r < 4; r++) {
        int row = m0 + wm * 128 + mf * 16 + quad * 4 + r;
        if (row < Mreal) {
#pragma unroll
          for (int nf = 0; nf < 4; nf++) {
            int col = n0 + wn * 64 + nf * 16 + l15;
            dst[(size_t)row * 1536 + col] = acc[mf][nf][r] + bcol[nf];
          }
        }
      }
  }
}

// mode 0 (432 blocks): [0,384) q-proj, then smalls; mode 1 (384): o-proj.
__global__ __launch_bounds__(512, 2) void gemm256(
    const u16* __restrict__ xbf, const u16* __restrict__ wqT,
    const float* __restrict__ bq, u16* __restrict__ qb,
    const u16* __restrict__ ctxb, const u16* __restrict__ wkT,
    const float* __restrict__ bk, u16* __restrict__ ktxt,
    const u16* __restrict__ wakT, const float* __restrict__ bak,
    u16* __restrict__ kimg, const u16* __restrict__ wvT,
    const float* __restrict__ bv, u16* __restrict__ vtt,
    const u16* __restrict__ wavT, const float* __restrict__ bav,
    u16* __restrict__ vti, const u16* __restrict__ yb,
    const u16* __restrict__ woT, const float* __restrict__ bo,
    float* __restrict__ out, int mode) {
  extern __shared__ u16 lds[];
  u16* As = lds;
  u16* Bs = lds + 32768;
  const int cpx = gridDim.x >> 3;  // grids are multiples of 8
  int id = (blockIdx.x & 7) * cpx + (blockIdx.x >> 3);
  const u16* ctxt = ctxb + 257 * 1536;
  const u16* A; const u16* Bt; const float* bias; void* outp;
  int Mreal, ldT, epi, bx, by;
  if (mode == 1) {
    A = yb; Bt = woT; bias = bo; outp = out;
    Mreal = 16384; ldT = 0; epi = 2; bx = id & 63; by = id >> 6;
  } else if (id < 384) {
    A = xbf; Bt = wqT; bias = bq; outp = qb;
    Mreal = 16384; ldT = 0; epi = 0; bx = id & 63; by = id >> 6;
  } else if (id < 396) {
    int t = id - 384;
    A = ctxt; Bt = wkT; bias = bk; outp = ktxt;
    Mreal = 512; ldT = 0; epi = 0; bx = t & 1; by = t >> 1;
  } else if (id < 408) {
    int t = id - 396;
    A = ctxb; Bt = wakT; bias = bak; outp = kimg;
    Mreal = 257; ldT = 0; epi = 0; bx = t & 1; by = t >> 1;
  } else if (id < 420) {
    int t = id - 408;
    A = ctxt; Bt = wvT; bias = bv; outp = vtt;
    Mreal = 512; ldT = 512; epi = 1; bx = t & 1; by = t >> 1;
  } else {
    int t = id - 420;
    A = ctxb; Bt = wavT; bias = bav; outp = vti;
    Mreal = 257; ldT = 264; epi = 1; bx = t & 1; by = t >> 1;
  }
  gemm256_core(A, Bt, bias, outp, Mreal, ldT, epi, bx, by, As, Bs);
}

// =====================================================================
// in-place RMSNorm over 1536 cols, bf16 buf, fp32 gain. One block per row.
// =====================================================================
__global__ __launch_bounds__(256) void rmsnorm_multi(
    u16* __restrict__ qb, const float* __restrict__ gq,
    u16* __restrict__ ktxt, const float* __restrict__ gk,
    u16* __restrict__ kimg, const float* __restrict__ gak) {
  int row = blockIdx.x;
  u16* buf; const float* g;
  if (row < 16384) {
    buf = qb; g = gq;
  } else if (row < 16896) {
    buf = ktxt; g = gk; row -= 16384;
  } else {
    buf = kimg; g = gak; row -= 16896;
  }
  const int tid = threadIdx.x;
  u32* p = (u32*)(buf + (size_t)row * 1536);  // 768 u32 per row
  const float2* g2 = (const float2*)g;
  u32 d[3];
  float v[6];
  float ss = 0.f;
#pragma unroll
  for (int j = 0; j < 3; j++) {
    d[j] = p[tid + j * 256];
    v[2 * j]     = bs2f((u16)(d[j] & 0xffffu));
    v[2 * j + 1] = bs2f((u16)(d[j] >> 16));
    ss += v[2 * j] * v[2 * j] + v[2 * j + 1] * v[2 * j + 1];
  }
#pragma unroll
  for (int off = 32; off; off >>= 1) ss += __shfl_xor(ss, off);
  __shared__ float red[4];
  if ((tid & 63) == 0) red[tid >> 6] = ss;
  __syncthreads();
  ss = red[0] + red[1] + red[2] + red[3];
  const float sc = rsqrtf(ss * (1.0f / 1536.0f) + 1e-6f);
#pragma unroll
  for (int j = 0; j < 3; j++) {
    float2 gg = g2[tid + j * 256];
    p[tid + j * 256] =
        cvtpk_bf16(v[2 * j] * sc * gg.x, v[2 * j + 1] * sc * gg.y);
  }
}

// =====================================================================
// Fused dual-segment attention, PIPELINED (T3-minimum / T14 recipe).
// Flat 13-iteration loop over K/V tiles (img t=0..4, txt t=5..12) with
// double-buffered K AND V LDS. Per iter: issue stage(t+1) FIRST, then
// QK -> softmax -> P -> PV on buf[t&1], then ONE __syncthreads (its
// vmcnt(0) drain covers stage(t+1), which had the whole iteration to
// fly -> effectively free). Stage latency fully hidden; barriers/iter
// halved. Ps shrunk to 16 rows/wave (rt-sequenced write/read; DS FIFO
// ordering makes the in-place reuse safe) so LDS = 2x16+2x16+9 = 73 KB
// -> 2 blocks/CU retained.
// Softmax: FIXED max 0 (rmsnormed q,k, scale 1/sqrt(128)); masked tile
// only at t==4 (img keys 257..319 read finite garbage, zeroed pre-exp).
// =====================================================================
#define ATTN_SCALE 0.08838834764831845f
__global__ __launch_bounds__(256, 2) void attn_kernel(
    const u16* __restrict__ q, const u16* __restrict__ ktxt,
    const u16* __restrict__ kimg, const u16* __restrict__ vttxt,
    const u16* __restrict__ vtimg, u16* __restrict__ y) {
  __shared__ u16 Ks[2][64 * 128];   // 2x16 KB, key-interleaved, xor-swizzled
  __shared__ u16 Vs[2][128 * 64];   // 2x16 KB, feat-major, xor-swizzled
  __shared__ u16 Ps[4 * 16 * 72];   // 9 KB, per-wave 16-row P (rt-sequenced)
  const int tid = threadIdx.x;
  const int w = tid >> 6, lane = tid & 63;
  const int quad = lane >> 4, l15 = lane & 15;
  const int h = blockIdx.y, hoff = h * 128;
  const int mw = blockIdx.x * 128 + w * 32;
  u16* Pw = Ps + w * (16 * 72);

  // Q frags (A-layout), resident
  bfrag qf[2][4];
#pragma unroll
  for (int rt = 0; rt < 2; rt++) {
    const u16* qrow = q + (size_t)(mw + rt * 16 + l15) * 1536 + hoff + quad * 8;
#pragma unroll
    for (int c = 0; c < 4; c++) qf[rt][c] = *(const bfrag*)(qrow + c * 32);
  }

  // staging descriptors: i = j*256+tid indexes 16B chunks in LDS-linear order
  int kko[4], kco[4], vfe[4], vco[4];
#pragma unroll
  for (int j = 0; j < 4; j++) {
    int i = j * 256 + tid;
    int s = i >> 4, cp = i & 15;           // K: slot s, chunk pos cp
    kko[j] = 4 * (s & 15) + (s >> 4);      // actual key for slot s
    kco[j] = ((cp ^ (s & 7)) * 8);         // swizzled feat offset (u16)
    int f = i >> 3, cq = i & 7;            // V: feat row f, chunk pos cq
    vfe[j] = f;
    vco[j] = ((cq ^ (f & 7)) * 8);         // swizzled key offset (u16)
  }

  f4 o[2][8];
  u32 resA[2][8][2];  // seg0 (img) result, normalized, bf16-packed
  float lr[2][4];
#pragma unroll
  for (int rt = 0; rt < 2; rt++) {
#pragma unroll
    for (int ft = 0; ft < 8; ft++) o[rt][ft] = f4{0.f, 0.f, 0.f, 0.f};
#pragma unroll
    for (int r = 0; r < 4; r++) lr[rt][r] = 0.f;
  }

  // prologue: stage tile 0 (img) into buf 0, drain, publish
#pragma unroll
  for (int j = 0; j < 4; j++)
    gl2lds16(kimg + (size_t)kko[j] * 1536 + hoff + kco[j],
             Ks[0] + (j * 256 + w * 64) * 8);
#pragma unroll
  for (int j = 0; j < 4; j++)
    gl2lds16(vtimg + (size_t)(hoff + vfe[j]) * 264 + vco[j],
             Vs[0] + (j * 256 + w * 64) * 8);
  __syncthreads();

  for (int t = 0; t < 13; ++t) {
    if (t == 5) {
      // ---- finalize seg0 (img): reduce l, pack normalized result
#pragma unroll
      for (int rt = 0; rt < 2; rt++)
#pragma unroll
        for (int r = 0; r < 4; r++) {
          float v = lr[rt][r];
          v += __shfl_xor(v, 1);
          v += __shfl_xor(v, 2);
          v += __shfl_xor(v, 4);
          v += __shfl_xor(v, 8);
          lr[rt][r] = 1.0f / v;
        }
#pragma unroll
      for (int rt = 0; rt < 2; rt++)
#pragma unroll
        for (int ft = 0; ft < 8; ft++) {
          resA[rt][ft][0] = cvtpk_bf16(o[rt][ft][0] * lr[rt][0],
                                       o[rt][ft][1] * lr[rt][1]);
          resA[rt][ft][1] = cvtpk_bf16(o[rt][ft][2] * lr[rt][2],
                                       o[rt][ft][3] * lr[rt][3]);
          o[rt][ft] = f4{0.f, 0.f, 0.f, 0.f};
        }
#pragma unroll
      for (int rt = 0; rt < 2; rt++)
#pragma unroll
        for (int r = 0; r < 4; r++) lr[rt][r] = 0.f;
    }

    const u16* Kb = Ks[t & 1];
    const u16* Vb = Vs[t & 1];

    // ---- issue stage(t+1) FIRST (latency hides under this iter's compute)
    if (t < 12) {
      const int tn = t + 1;
      const u16* kp; const u16* vp; int t0n, ldv;
      if (tn < 5) { kp = kimg; vp = vtimg; t0n = tn * 64; ldv = 264; }
      else        { kp = ktxt; vp = vttxt; t0n = (tn - 5) * 64; ldv = 512; }
      u16* Kd = Ks[tn & 1];
      u16* Vd = Vs[tn & 1];
#pragma unroll
      for (int j = 0; j < 4; j++)
        gl2lds16(kp + (size_t)(t0n + kko[j]) * 1536 + hoff + kco[j],
                 Kd + (j * 256 + w * 64) * 8);
#pragma unroll
      for (int j = 0; j < 4; j++)
        gl2lds16(vp + (size_t)(hoff + vfe[j]) * ldv + t0n + vco[j],
                 Vd + (j * 256 + w * 64) * 8);
    }

    // ---- S = Q K^T (32 MFMA); kf shared across both rowtiles
    f4 s[2][4];
#pragma unroll
    for (int rt = 0; rt < 2; rt++)
#pragma unroll
      for (int tt = 0; tt < 4; tt++) s[rt][tt] = f4{0.f, 0.f, 0.f, 0.f};
#pragma unroll
    for (int tt = 0; tt < 4; tt++) {
      const u16* kb = Kb + (tt * 16 + l15) * 128;
      bfrag kf[4];
#pragma unroll
      for (int c = 0; c < 4; c++)
        kf[c] = *(const bfrag*)(kb + (((c * 4 + quad) ^ (l15 & 7)) * 8));
#pragma unroll
      for (int rt = 0; rt < 2; rt++)
#pragma unroll
        for (int c = 0; c < 4; c++)
          s[rt][tt] = MFMA(qf[rt][c], kf[c], s[rt][tt]);
    }

    // ---- softmax, fixed max = 0; only tile 4 (img keys 256..319) masked
    if (t != 4) {
#pragma unroll
      for (int rt = 0; rt < 2; rt++)
#pragma unroll
        for (int tt = 0; tt < 4; tt++)
#pragma unroll
          for (int r = 0; r < 4; r++) {
            float p = __expf(s[rt][tt][r] * ATTN_SCALE);
            s[rt][tt][r] = p;
            lr[rt][r] += p;
          }
    } else {
#pragma unroll
      for (int tt = 0; tt < 4; tt++) {
        bool ok = (256 + 4 * l15 + tt) < 257;
#pragma unroll
        for (int rt = 0; rt < 2; rt++)
#pragma unroll
          for (int r = 0; r < 4; r++) {
            float p = ok ? __expf(s[rt][tt][r] * ATTN_SCALE) : 0.f;
            s[rt][tt][r] = p;
            lr[rt][r] += p;
          }
      }
    }

    // ---- P transpose via 16-row Ps, rt-sequenced (in-place reuse is safe:
    // DS ops execute in order per wave; rt0 reads precede rt1 writes)
    bfrag pf[2][2];
#pragma unroll
    for (int rt = 0; rt < 2; rt++) {
#pragma unroll
      for (int r = 0; r < 4; r++) {
        u32 lo = cvtpk_bf16(s[rt][0][r], s[rt][1][r]);
        u32 hi = cvtpk_bf16(s[rt][2][r], s[rt][3][r]);
        *(uint2*)(Pw + (quad * 4 + r) * 72 + l15 * 4) = make_uint2(lo, hi);
      }
      asm volatile("s_waitcnt lgkmcnt(0)" ::: "memory");
#pragma unroll
      for (int hf = 0; hf < 2; hf++)
        pf[rt][hf] = *(const bfrag*)(Pw + l15 * 72 + hf * 32 + quad * 8);
    }

    // ---- O += P V (32 MFMA); vf shared across rowtiles
#pragma unroll
    for (int ft = 0; ft < 8; ft++) {
      const u16* vb = Vb + (ft * 16 + l15) * 64;
#pragma unroll
      for (int hf = 0; hf < 2; hf++) {
        bfrag vf = *(const bfrag*)(vb + (((hf * 4 + quad) ^ (l15 & 7)) * 8));
#pragma unroll
        for (int rt = 0; rt < 2; rt++)
          o[rt][ft] = MFMA(pf[rt][hf], vf, o[rt][ft]);
      }
    }

    // ---- single barrier: drains vmcnt (stage t+1 landed on all waves),
    // publishes Ks/Vs[(t+1)&1], and protects buf[t&1] for restage at t+1.
    __syncthreads();
  }

  // ---- finalize seg1 (txt): reduce l
#pragma unroll
  for (int rt = 0; rt < 2; rt++)
#pragma unroll
    for (int r = 0; r < 4; r++) {
      float v = lr[rt][r];
      v += __shfl_xor(v, 1);
      v += __shfl_xor(v, 2);
      v += __shfl_xor(v, 4);
      v += __shfl_xor(v, 8);
      lr[rt][r] = 1.0f / v;
    }

  // ---- epilogue: y = img_norm + txt_norm (bf16)
#pragma unroll
  for (int rt = 0; rt < 2; rt++)
#pragma unroll
    for (int ft = 0; ft < 8; ft++) {
      float ra[4];
      ra[0] = bs2f((u16)(resA[rt][ft][0] & 0xffffu));
      ra[1] = bs2f((u16)(resA[rt][ft][0] >> 16));
      ra[2] = bs2f((u16)(resA[rt][ft][1] & 0xffffu));
      ra[3] = bs2f((u16)(resA[rt][ft][1] >> 16));
#pragma unroll
      for (int r = 0; r < 4; r++)
        y[(size_t)(mw + rt * 16 + quad * 4 + r) * 1536 + hoff + ft * 16 + l15] =
            f2bs(ra[r] + o[rt][ft][r] * lr[rt][r]);
    }
}

// =====================================================================
extern "C" void kernel_launch(void* const* d_in, const int* in_sizes, int n_in,
                              void* d_out, int out_size, void* d_ws,
                              size_t ws_size, hipStream_t stream) {
  const float* x   = (const float*)d_in[0];
  const float* ctx = (const float*)d_in[1];
  const float* Wq  = (const float*)d_in[3];
  const float* bq  = (const float*)d_in[4];
  const float* Wk  = (const float*)d_in[5];
  const float* bk  = (const float*)d_in[6];
  const float* Wv  = (const float*)d_in[7];
  const float* bv  = (const float*)d_in[8];
  const float* Wak = (const float*)d_in[9];
  const float* bak = (const float*)d_in[10];
  const float* Wav = (const float*)d_in[11];
  const float* bav = (const float*)d_in[12];
  const float* Wo  = (const float*)d_in[13];
  const float* bo  = (const float*)d_in[14];
  const float* gq  = (const float*)d_in[15];
  const float* gk  = (const float*)d_in[16];
  const float* gak = (const float*)d_in[17];
  float* out = (float*)d_out;

  // workspace layout (u16 elements); ~136 MB
  // NOTE: attn over-reads kimg rows [257,320) -> lands in vti (finite bf16,
  // masked) and vti cols beyond 264 -> stays within vti/vtt (finite, P==0).
  // gemm256 small-GEMM paths over-read A rows up to 511 -> stay inside ctxb.
  u16* xbf  = (u16*)d_ws;                 // 16384x1536 bf16 x; reused as y later
  u16* qb   = xbf + 25165824;             // 16384x1536 q
  u16* ctxb = qb + 25165824;              // 769x1536 context bf16
  u16* wqT  = ctxb + 1181184;             // 6 transposed bf16 weights (NxK)
  u16* wkT  = wqT + 2359296;
  u16* wvT  = wkT + 2359296;
  u16* wakT = wvT + 2359296;
  u16* wavT = wakT + 2359296;
  u16* woT  = wavT + 2359296;
  u16* ktxt = woT + 2359296;              // 512x1536
  u16* kimg = ktxt + 786432;              // 257x1536
  u16* vti  = kimg + 394752;              // V^T img: 1536x264
  u16* vtt  = vti + 405504;               // V^T txt: 1536x512 (exact, last)

  // 1) fused dtype conversions + weight transposes (one launch)
  prep<<<26689, 256, 0, stream>>>(x, xbf, ctx, ctxb,
                                  Wq, Wk, Wv, Wak, Wav, Wo,
                                  wqT, wkT, wvT, wakT, wavT, woT);

  // 2) all five projections in ONE deep-pipelined launch (128 KiB dyn LDS)
  gemm256<<<432, 512, 131072, stream>>>(xbf, wqT, bq, qb,
                                        ctxb, wkT, bk, ktxt,
                                        wakT, bak, kimg,
                                        wvT, bv, vtt,
                                        wavT, bav, vti,
                                        xbf, woT, bo, out, 0);

  // 3) RMSNorms (in-place, full 1536-dim rows), one launch for q/k/k_img
  rmsnorm_multi<<<17153, 256, 0, stream>>>(qb, gq, ktxt, gk, kimg, gak);

  // 4) fused dual attention -> y (reuses xbf region)
  attn_kernel<<<dim3(128, 12), 256, 0, stream>>>(qb, ktxt, kimg, vtt, vti, xbf);

  // 5) output projection, fp32 (same kernel, mode 1)
  gemm256<<<384, 512, 131072, stream>>>(xbf, wqT, bq, qb,
                                        ctxb, wkT, bk, ktxt,
                                        wakT, bak, kimg,
                                        wvT, bv, vtt,
                                        wavT, bav, vti,
                                        xbf, woT, bo, out, 1);
}